// Round 5
// baseline (641.184 us; speedup 1.0000x reference)
//
#include <hip/hip_runtime.h>

typedef unsigned short u16;
typedef unsigned int u32;
typedef __attribute__((ext_vector_type(8))) short bf16x8;
typedef __attribute__((ext_vector_type(4))) float f32x4;
typedef __attribute__((ext_vector_type(8))) u16 u16x8;
typedef __attribute__((ext_vector_type(4))) u16 u16x4;

#define DEV __device__ __forceinline__

DEV u16 f2bf(float f) {
  u32 x = __float_as_uint(f);
  return (u16)((x + 0x7fffu + ((x >> 16) & 1u)) >> 16);  // RNE
}

// Problem dims: B=8 S=512 H=768 E=8 F=3072 K=2. fp32 I/O; internal bf16 MFMA.

#define LDAB 72  // LDS row stride in elems (144 B = 36 dwords): conflict-free floor
                 // for both b128 fragment reads and b128 staging writes

// ---------- convert hidden fp32->bf16 + pooled sums ----------
__global__ void convert_pool_kernel(const float* __restrict__ hidden, u16* __restrict__ hbf,
                                    float* __restrict__ pooled) {
  const int b = blockIdx.y, chunk = blockIdx.x, t = threadIdx.x;  // t in [0,192)
  const size_t base = (size_t)b * 512 * 768 + (size_t)chunk * 8 * 768 + t * 4;
  float ax = 0.f, ay = 0.f, az = 0.f, aw = 0.f;
#pragma unroll
  for (int r = 0; r < 8; ++r) {
    const float4 v = *(const float4*)(hidden + base + r * 768);
    ax += v.x; ay += v.y; az += v.z; aw += v.w;
    u16x4 o; o[0] = f2bf(v.x); o[1] = f2bf(v.y); o[2] = f2bf(v.z); o[3] = f2bf(v.w);
    *(u16x4*)(hbf + base + r * 768) = o;
  }
  float* p = pooled + b * 768 + t * 4;
  atomicAdd(p + 0, ax); atomicAdd(p + 1, ay);
  atomicAdd(p + 2, az); atomicAdd(p + 3, aw);
}

// ---------- router finalize ----------
__global__ void router_final_kernel(const float* __restrict__ pooled, const float* __restrict__ Wg,
                                    float* __restrict__ logits_out, int* __restrict__ sel,
                                    float* __restrict__ wsel) {
  __shared__ float l8[64];
  const int tid = threadIdx.x;
  const int b = tid >> 5, r = tid & 31, e = r >> 2, q = r & 3;
  float p = 0.f;
  for (int h = q * 192; h < q * 192 + 192; ++h) p += pooled[b * 768 + h] * Wg[h * 8 + e];
  p += __shfl_xor(p, 1);
  p += __shfl_xor(p, 2);
  if (q == 0) {
    const float lg = p * (1.f / 512.f);
    l8[b * 8 + e] = lg;
    logits_out[b * 8 + e] = lg;
  }
  __syncthreads();
  if (tid < 8) {
    const int bb = tid;
    float mx = -1e30f;
    for (int i = 0; i < 8; ++i) mx = fmaxf(mx, l8[bb * 8 + i]);
    float w[8], ssum = 0.f;
    for (int i = 0; i < 8; ++i) { w[i] = __expf(l8[bb * 8 + i] - mx); ssum += w[i]; }
    for (int i = 0; i < 8; ++i) w[i] /= ssum;
    int i0 = 0;
    for (int i = 1; i < 8; ++i) if (w[i] > w[i0]) i0 = i;   // first-occurrence ties
    int i1 = (i0 == 0) ? 1 : 0;
    for (int i = 0; i < 8; ++i) if (i != i0 && w[i] > w[i1]) i1 = i;
    sel[bb * 2 + 0] = i0; sel[bb * 2 + 1] = i1;
    wsel[bb * 2 + 0] = w[i0]; wsel[bb * 2 + 1] = w[i1];
  }
}

// ---------- 64x64 tiled transpose, fp32 src -> bf16 dst ----------
__global__ void transpose_kernel(const float* __restrict__ src, u16* __restrict__ dst,
                                 int R, int C) {
  __shared__ u16 tile[64][68];
  const int e = blockIdx.z;
  src += (size_t)e * (size_t)R * C;
  dst += (size_t)e * (size_t)R * C;
  const int r0 = blockIdx.y * 64, c0 = blockIdx.x * 64;
  const int t = threadIdx.x;  // [0,128)
#pragma unroll
  for (int i = 0; i < 8; ++i) {
    const int ch = i * 128 + t;
    const int row = ch >> 4, c4 = (ch & 15) * 4;
    const float4 v = *(const float4*)(src + (size_t)(r0 + row) * C + c0 + c4);
    u16x4 o; o[0] = f2bf(v.x); o[1] = f2bf(v.y); o[2] = f2bf(v.z); o[3] = f2bf(v.w);
    *(u16x4*)(&tile[row][c4]) = o;
  }
  __syncthreads();
  const int cg = t & 15, rg = t >> 4;
  const int c4 = cg * 4, r8 = rg * 8;
  u16x4 rv[8];
#pragma unroll
  for (int j = 0; j < 8; ++j) rv[j] = *(const u16x4*)(&tile[r8 + j][c4]);
#pragma unroll
  for (int i = 0; i < 4; ++i) {
    u16x8 o;
#pragma unroll
    for (int j = 0; j < 8; ++j) o[j] = rv[j][i];
    *(u16x8*)(dst + (size_t)(c0 + c4 + i) * R + r0 + r8) = o;
  }
}

// ---------- pipelined GEMM core: global->VGPR prefetch, ds_write staging ----------
// tile 128x128, BK=64. Per thread per tile: 4 x 16B chunks, chunk c=i*256+tid,
// row=c>>3, koff=(c&7)*8 — identical linear mapping for load and LDS store.
DEV void load_tile(const u16* __restrict__ g, int ld, int row0, int k0, int tid, uint4 r[4]) {
#pragma unroll
  for (int i = 0; i < 4; ++i) {
    const int c = i * 256 + tid, row = c >> 3, ko = (c & 7) * 8;
    r[i] = *(const uint4*)(g + (size_t)(row0 + row) * ld + k0 + ko);
  }
}
DEV void store_tile_lds(u16* lds, int tid, const uint4 r[4]) {
#pragma unroll
  for (int i = 0; i < 4; ++i) {
    const int c = i * 256 + tid, row = c >> 3, ko = (c & 7) * 8;
    *(uint4*)(lds + row * LDAB + ko) = r[i];
  }
}

DEV void mfma_step(const u16* As, const u16* Bs, int wm, int wn, int mi, int kq,
                   f32x4 acc[4][4]) {
#pragma unroll
  for (int s2 = 0; s2 < 64; s2 += 32) {
    bf16x8 af[4], bfr[4];
#pragma unroll
    for (int mt = 0; mt < 4; ++mt)
      af[mt] = *(const bf16x8*)(As + (wm + mt * 16 + mi) * LDAB + s2 + kq * 8);
#pragma unroll
    for (int nt = 0; nt < 4; ++nt)
      bfr[nt] = *(const bf16x8*)(Bs + (wn + nt * 16 + mi) * LDAB + s2 + kq * 8);
#pragma unroll
    for (int mt = 0; mt < 4; ++mt)
#pragma unroll
      for (int nt = 0; nt < 4; ++nt)
        acc[mt][nt] = __builtin_amdgcn_mfma_f32_16x16x32_bf16(af[mt], bfr[nt], acc[mt][nt], 0, 0, 0);
  }
}

// ---------- GEMM1: hbuf = wgt * gelu(hbf @ W1[e] + b1[e]), bf16 out ----------
// grid (24 n, 4 m, 16 pairs); K=768 -> 12 steps
__global__ void gemm1_kernel(const u16* __restrict__ hbf, const u16* __restrict__ w1t,
                             const float* __restrict__ b1, u16* __restrict__ hbuf,
                             const int* __restrict__ sel, const float* __restrict__ wsel) {
  __shared__ __align__(16) u16 As[128 * LDAB];
  __shared__ __align__(16) u16 Bs[128 * LDAB];
  const int p = blockIdx.z;
  const int b = p >> 1;
  const int e = sel[p];
  const float wgt = wsel[p];
  const u16* A = hbf + (size_t)b * 512 * 768;
  const u16* Bt = w1t + (size_t)e * 3072 * 768;
  const int m0 = blockIdx.y * 128, n0 = blockIdx.x * 128;
  const int tid = threadIdx.x, lane = tid & 63;
  const int wv = tid >> 6;
  const int wm = (wv >> 1) * 64, wn = (wv & 1) * 64;
  const int mi = lane & 15, kq = lane >> 4;

  uint4 ra[4], rb[4];
  load_tile(A, 768, m0, 0, tid, ra);
  load_tile(Bt, 768, n0, 0, tid, rb);
  f32x4 acc[4][4] = {};
  for (int t = 0; t < 12; ++t) {
    __syncthreads();               // all waves done reading LDS of step t-1
    store_tile_lds(As, tid, ra);   // compiler waits vmcnt only for ra/rb here
    store_tile_lds(Bs, tid, rb);
    __syncthreads();
    if (t + 1 < 12) {              // prefetch t+1: overlaps mfma_step(t)
      load_tile(A, 768, m0, (t + 1) * 64, tid, ra);
      load_tile(Bt, 768, n0, (t + 1) * 64, tid, rb);
    }
    mfma_step(As, Bs, wm, wn, mi, kq, acc);
  }

  const float* b1e = b1 + e * 3072;
  u16* C = hbuf + (size_t)p * 512 * 3072;
#pragma unroll
  for (int nt = 0; nt < 4; ++nt) {
    const int col = n0 + wn + nt * 16 + mi;
    const float bias = b1e[col];
#pragma unroll
    for (int mt = 0; mt < 4; ++mt) {
#pragma unroll
      for (int r = 0; r < 4; ++r) {
        const int row = m0 + wm + mt * 16 + kq * 4 + r;  // C/D: col=lane&15, row=quad*4+reg
        const float x = acc[mt][nt][r] + bias;
        const float g = 0.5f * x * (1.f + erff(x * 0.70710678118654752f));  // exact GELU
        C[(size_t)row * 3072 + col] = f2bf(wgt * g);
      }
    }
  }
}

// ---------- GEMM2 split-K x4: out[b] += hbuf_k @ W2[e_k] (fp32 atomics) ----------
// grid (6 n, 4 m, 32 = 8 b x 4 ks); each split = 24 steps. ks==0 adds weighted bias
// (out was memset to 0 before launch).
__global__ void gemm2_kernel(const u16* __restrict__ hbuf, const u16* __restrict__ w2t,
                             const float* __restrict__ b2, float* __restrict__ out,
                             const int* __restrict__ sel, const float* __restrict__ wsel) {
  __shared__ __align__(16) u16 As[128 * LDAB];
  __shared__ __align__(16) u16 Bs[128 * LDAB];
  const int z = blockIdx.z;
  const int b = z >> 2, ks = z & 3;
  const int kslot = ks >> 1;
  const int e = sel[b * 2 + kslot];
  const u16* A = hbuf + (size_t)(b * 2 + kslot) * 512 * 3072;
  const u16* Bt = w2t + (size_t)e * 768 * 3072;
  const int kbase = (ks & 1) * 1536;
  const int m0 = blockIdx.y * 128, n0 = blockIdx.x * 128;
  const int tid = threadIdx.x, lane = tid & 63;
  const int wv = tid >> 6;
  const int wm = (wv >> 1) * 64, wn = (wv & 1) * 64;
  const int mi = lane & 15, kq = lane >> 4;

  uint4 ra[4], rb[4];
  load_tile(A, 3072, m0, kbase, tid, ra);
  load_tile(Bt, 3072, n0, kbase, tid, rb);
  f32x4 acc[4][4] = {};
  for (int t = 0; t < 24; ++t) {
    __syncthreads();
    store_tile_lds(As, tid, ra);
    store_tile_lds(Bs, tid, rb);
    __syncthreads();
    if (t + 1 < 24) {
      load_tile(A, 3072, m0, kbase + (t + 1) * 64, tid, ra);
      load_tile(Bt, 3072, n0, kbase + (t + 1) * 64, tid, rb);
    }
    mfma_step(As, Bs, wm, wn, mi, kq, acc);
  }

  float* C = out + (size_t)b * 512 * 768;
  const float w0 = wsel[b * 2 + 0], w1 = wsel[b * 2 + 1];
  const float* b2e0 = b2 + sel[b * 2 + 0] * 768;
  const float* b2e1 = b2 + sel[b * 2 + 1] * 768;
#pragma unroll
  for (int nt = 0; nt < 4; ++nt) {
    const int col = n0 + wn + nt * 16 + mi;
    const float bias = (ks == 0) ? (w0 * b2e0[col] + w1 * b2e1[col]) : 0.f;
#pragma unroll
    for (int mt = 0; mt < 4; ++mt) {
#pragma unroll
      for (int r = 0; r < 4; ++r) {
        const int row = m0 + wm + mt * 16 + kq * 4 + r;
        atomicAdd(&C[(size_t)row * 768 + col], acc[mt][nt][r] + bias);
      }
    }
  }
}

extern "C" void kernel_launch(void* const* d_in, const int* in_sizes, int n_in,
                              void* d_out, int out_size, void* d_ws, size_t ws_size,
                              hipStream_t stream) {
  const float* hidden = (const float*)d_in[0];  // [8,512,768] fp32
  const float* Wg     = (const float*)d_in[1];  // [768,8]
  const float* W1     = (const float*)d_in[2];  // [8,768,3072]
  const float* b1     = (const float*)d_in[3];  // [8,3072]
  const float* W2     = (const float*)d_in[4];  // [8,3072,768]
  const float* b2     = (const float*)d_in[5];  // [8,768]
  float* out = (float*)d_out;                   // [8,512,768] ++ logits [8,8], fp32

  char* ws = (char*)d_ws;
  int*   sel    = (int*)ws;                     // [16]
  float* wsel   = (float*)(ws + 64);            // [16]
  float* pooled = (float*)(ws + 128);           // [8][768] fp32
  u16* hbf  = (u16*)(ws + 32768);               // [8][512][768] bf16
  u16* wT   = hbf + (size_t)8 * 512 * 768;      // [8][3072][768] bf16 (w1t, then w2t)
  u16* hbuf = wT + (size_t)8 * 3072 * 768;      // [16][512][3072] bf16

  float* logits_out = out + (size_t)8 * 512 * 768;

  hipMemsetAsync(ws, 0, 32768, stream);                       // sel/wsel/pooled
  hipMemsetAsync(out, 0, (size_t)out_size * 4, stream);       // atomic accum base
  convert_pool_kernel<<<dim3(64, 8), 192, 0, stream>>>(hidden, hbf, pooled);
  router_final_kernel<<<1, 256, 0, stream>>>(pooled, Wg, logits_out, sel, wsel);
  transpose_kernel<<<dim3(48, 12, 8), 128, 0, stream>>>(W1, wT, 768, 3072);   // [H,F]->[F,H]
  gemm1_kernel<<<dim3(24, 4, 16), 256, 0, stream>>>(hbf, wT, b1, hbuf, sel, wsel);
  transpose_kernel<<<dim3(12, 48, 8), 128, 0, stream>>>(W2, wT, 3072, 768);   // [F,H]->[H,F]
  gemm2_kernel<<<dim3(6, 4, 32), 256, 0, stream>>>(hbuf, wT, b2, out, sel, wsel);
}

// Round 6
// 636.507 us; speedup vs baseline: 1.0073x; 1.0073x over previous
//
#include <hip/hip_runtime.h>

typedef unsigned short u16;
typedef unsigned int u32;
typedef __attribute__((ext_vector_type(8))) short bf16x8;
typedef __attribute__((ext_vector_type(4))) float f32x4;
typedef __attribute__((ext_vector_type(8))) u16 u16x8;
typedef __attribute__((ext_vector_type(4))) u16 u16x4;

#define DEV __device__ __forceinline__

DEV u16 f2bf(float f) {
  u32 x = __float_as_uint(f);
  return (u16)((x + 0x7fffu + ((x >> 16) & 1u)) >> 16);  // RNE
}

// Problem dims: B=8 S=512 H=768 E=8 F=3072 K=2. fp32 I/O; internal bf16 MFMA.

#define LDAB 72  // LDS row stride (144 B): b128 reads+writes conflict-free (2-way max)

// ---------- convert hidden fp32->bf16 + pooled sums ----------
__global__ void convert_pool_kernel(const float* __restrict__ hidden, u16* __restrict__ hbf,
                                    float* __restrict__ pooled) {
  const int b = blockIdx.y, chunk = blockIdx.x, t = threadIdx.x;  // t in [0,192)
  const size_t base = (size_t)b * 512 * 768 + (size_t)chunk * 8 * 768 + t * 4;
  float ax = 0.f, ay = 0.f, az = 0.f, aw = 0.f;
#pragma unroll
  for (int r = 0; r < 8; ++r) {
    const float4 v = *(const float4*)(hidden + base + r * 768);
    ax += v.x; ay += v.y; az += v.z; aw += v.w;
    u16x4 o; o[0] = f2bf(v.x); o[1] = f2bf(v.y); o[2] = f2bf(v.z); o[3] = f2bf(v.w);
    *(u16x4*)(hbf + base + r * 768) = o;
  }
  float* p = pooled + b * 768 + t * 4;
  atomicAdd(p + 0, ax); atomicAdd(p + 1, ay);
  atomicAdd(p + 2, az); atomicAdd(p + 3, aw);
}

// ---------- router finalize ----------
__global__ void router_final_kernel(const float* __restrict__ pooled, const float* __restrict__ Wg,
                                    float* __restrict__ logits_out, int* __restrict__ sel,
                                    float* __restrict__ wsel) {
  __shared__ float l8[64];
  const int tid = threadIdx.x;
  const int b = tid >> 5, r = tid & 31, e = r >> 2, q = r & 3;
  float p = 0.f;
  for (int h = q * 192; h < q * 192 + 192; ++h) p += pooled[b * 768 + h] * Wg[h * 8 + e];
  p += __shfl_xor(p, 1);
  p += __shfl_xor(p, 2);
  if (q == 0) {
    const float lg = p * (1.f / 512.f);
    l8[b * 8 + e] = lg;
    logits_out[b * 8 + e] = lg;
  }
  __syncthreads();
  if (tid < 8) {
    const int bb = tid;
    float mx = -1e30f;
    for (int i = 0; i < 8; ++i) mx = fmaxf(mx, l8[bb * 8 + i]);
    float w[8], ssum = 0.f;
    for (int i = 0; i < 8; ++i) { w[i] = __expf(l8[bb * 8 + i] - mx); ssum += w[i]; }
    for (int i = 0; i < 8; ++i) w[i] /= ssum;
    int i0 = 0;
    for (int i = 1; i < 8; ++i) if (w[i] > w[i0]) i0 = i;   // first-occurrence ties
    int i1 = (i0 == 0) ? 1 : 0;
    for (int i = 0; i < 8; ++i) if (i != i0 && w[i] > w[i1]) i1 = i;
    sel[bb * 2 + 0] = i0; sel[bb * 2 + 1] = i1;
    wsel[bb * 2 + 0] = w[i0]; wsel[bb * 2 + 1] = w[i1];
  }
}

// ---------- 64x64 tiled transpose, fp32 src -> bf16 dst ----------
__global__ void transpose_kernel(const float* __restrict__ src, u16* __restrict__ dst,
                                 int R, int C) {
  __shared__ u16 tile[64][68];
  const int e = blockIdx.z;
  src += (size_t)e * (size_t)R * C;
  dst += (size_t)e * (size_t)R * C;
  const int r0 = blockIdx.y * 64, c0 = blockIdx.x * 64;
  const int t = threadIdx.x;  // [0,128)
#pragma unroll
  for (int i = 0; i < 8; ++i) {
    const int ch = i * 128 + t;
    const int row = ch >> 4, c4 = (ch & 15) * 4;
    const float4 v = *(const float4*)(src + (size_t)(r0 + row) * C + c0 + c4);
    u16x4 o; o[0] = f2bf(v.x); o[1] = f2bf(v.y); o[2] = f2bf(v.z); o[3] = f2bf(v.w);
    *(u16x4*)(&tile[row][c4]) = o;
  }
  __syncthreads();
  const int cg = t & 15, rg = t >> 4;
  const int c4 = cg * 4, r8 = rg * 8;
  u16x4 rv[8];
#pragma unroll
  for (int j = 0; j < 8; ++j) rv[j] = *(const u16x4*)(&tile[r8 + j][c4]);
#pragma unroll
  for (int i = 0; i < 4; ++i) {
    u16x8 o;
#pragma unroll
    for (int j = 0; j < 8; ++j) o[j] = rv[j][i];
    *(u16x8*)(dst + (size_t)(c0 + c4 + i) * R + r0 + r8) = o;
  }
}

// ---------- pipelined GEMM core: global->VGPR prefetch, ds_write staging ----------
DEV void load_tile(const u16* __restrict__ g, int ld, int row0, int k0, int tid, uint4 r[4]) {
#pragma unroll
  for (int i = 0; i < 4; ++i) {
    const int c = i * 256 + tid, row = c >> 3, ko = (c & 7) * 8;
    r[i] = *(const uint4*)(g + (size_t)(row0 + row) * ld + k0 + ko);
  }
}
DEV void store_tile_lds(u16* lds, int tid, const uint4 r[4]) {
#pragma unroll
  for (int i = 0; i < 4; ++i) {
    const int c = i * 256 + tid, row = c >> 3, ko = (c & 7) * 8;
    *(uint4*)(lds + row * LDAB + ko) = r[i];
  }
}

DEV void mfma_step(const u16* As, const u16* Bs, int wm, int wn, int mi, int kq,
                   f32x4 acc[4][4]) {
#pragma unroll
  for (int s2 = 0; s2 < 64; s2 += 32) {
    bf16x8 af[4], bfr[4];
#pragma unroll
    for (int mt = 0; mt < 4; ++mt)
      af[mt] = *(const bf16x8*)(As + (wm + mt * 16 + mi) * LDAB + s2 + kq * 8);
#pragma unroll
    for (int nt = 0; nt < 4; ++nt)
      bfr[nt] = *(const bf16x8*)(Bs + (wn + nt * 16 + mi) * LDAB + s2 + kq * 8);
#pragma unroll
    for (int mt = 0; mt < 4; ++mt)
#pragma unroll
      for (int nt = 0; nt < 4; ++nt)
        acc[mt][nt] = __builtin_amdgcn_mfma_f32_16x16x32_bf16(af[mt], bfr[nt], acc[mt][nt], 0, 0, 0);
  }
}

// ---------- GEMM1: hbuf = wgt * gelu(hbf @ W1[e] + b1[e]), bf16 out ----------
// grid (24 n, 4 m, 16 pairs); K=768 -> 12 steps
__global__ void __launch_bounds__(256, 2)
gemm1_kernel(const u16* __restrict__ hbf, const u16* __restrict__ w1t,
             const float* __restrict__ b1, u16* __restrict__ hbuf,
             const int* __restrict__ sel, const float* __restrict__ wsel) {
  __shared__ __align__(16) u16 As[128 * LDAB];
  __shared__ __align__(16) u16 Bs[128 * LDAB];
  const int p = blockIdx.z;
  const int b = p >> 1;
  const int e = sel[p];
  const float wgt = wsel[p];
  const u16* A = hbf + (size_t)b * 512 * 768;
  const u16* Bt = w1t + (size_t)e * 3072 * 768;
  const int m0 = blockIdx.y * 128, n0 = blockIdx.x * 128;
  const int tid = threadIdx.x, lane = tid & 63;
  const int wv = tid >> 6;
  const int wm = (wv >> 1) * 64, wn = (wv & 1) * 64;
  const int mi = lane & 15, kq = lane >> 4;

  uint4 ra[4], rb[4];
  load_tile(A, 768, m0, 0, tid, ra);
  load_tile(Bt, 768, n0, 0, tid, rb);
  f32x4 acc[4][4] = {};
  for (int t = 0; t < 12; ++t) {
    __syncthreads();               // all waves done reading LDS of step t-1
    store_tile_lds(As, tid, ra);   // waits vmcnt only for ra/rb
    store_tile_lds(Bs, tid, rb);
    __syncthreads();
    if (t + 1 < 12) {              // prefetch t+1 overlaps mfma_step(t)
      load_tile(A, 768, m0, (t + 1) * 64, tid, ra);
      load_tile(Bt, 768, n0, (t + 1) * 64, tid, rb);
    }
    mfma_step(As, Bs, wm, wn, mi, kq, acc);
  }

  const float* b1e = b1 + e * 3072;
  u16* C = hbuf + (size_t)p * 512 * 3072;
#pragma unroll
  for (int nt = 0; nt < 4; ++nt) {
    const int col = n0 + wn + nt * 16 + mi;
    const float bias = b1e[col];
#pragma unroll
    for (int mt = 0; mt < 4; ++mt) {
#pragma unroll
      for (int r = 0; r < 4; ++r) {
        const int row = m0 + wm + mt * 16 + kq * 4 + r;  // C/D: col=lane&15, row=quad*4+reg
        const float x = acc[mt][nt][r] + bias;
        const float g = 0.5f * x * (1.f + erff(x * 0.70710678118654752f));  // exact GELU
        C[(size_t)row * 3072 + col] = f2bf(wgt * g);
      }
    }
  }
}

// ---------- GEMM2 split-K x4: out[b] += hbuf_k @ W2[e_k] (fp32 atomics) ----------
// grid (6 n, 4 m, 32 = 8 b x 4 ks); each split = 24 steps. ks==0 adds weighted bias.
__global__ void __launch_bounds__(256, 2)
gemm2_kernel(const u16* __restrict__ hbuf, const u16* __restrict__ w2t,
             const float* __restrict__ b2, float* __restrict__ out,
             const int* __restrict__ sel, const float* __restrict__ wsel) {
  __shared__ __align__(16) u16 As[128 * LDAB];
  __shared__ __align__(16) u16 Bs[128 * LDAB];
  const int z = blockIdx.z;
  const int b = z >> 2, ks = z & 3;
  const int kslot = ks >> 1;
  const int e = sel[b * 2 + kslot];
  const u16* A = hbuf + (size_t)(b * 2 + kslot) * 512 * 3072;
  const u16* Bt = w2t + (size_t)e * 768 * 3072;
  const int kbase = (ks & 1) * 1536;
  const int m0 = blockIdx.y * 128, n0 = blockIdx.x * 128;
  const int tid = threadIdx.x, lane = tid & 63;
  const int wv = tid >> 6;
  const int wm = (wv >> 1) * 64, wn = (wv & 1) * 64;
  const int mi = lane & 15, kq = lane >> 4;

  uint4 ra[4], rb[4];
  load_tile(A, 3072, m0, kbase, tid, ra);
  load_tile(Bt, 3072, n0, kbase, tid, rb);
  f32x4 acc[4][4] = {};
  for (int t = 0; t < 24; ++t) {
    __syncthreads();
    store_tile_lds(As, tid, ra);
    store_tile_lds(Bs, tid, rb);
    __syncthreads();
    if (t + 1 < 24) {
      load_tile(A, 3072, m0, kbase + (t + 1) * 64, tid, ra);
      load_tile(Bt, 3072, n0, kbase + (t + 1) * 64, tid, rb);
    }
    mfma_step(As, Bs, wm, wn, mi, kq, acc);
  }

  float* C = out + (size_t)b * 512 * 768;
  const float w0 = wsel[b * 2 + 0], w1 = wsel[b * 2 + 1];
  const float* b2e0 = b2 + sel[b * 2 + 0] * 768;
  const float* b2e1 = b2 + sel[b * 2 + 1] * 768;
#pragma unroll
  for (int nt = 0; nt < 4; ++nt) {
    const int col = n0 + wn + nt * 16 + mi;
    const float bias = (ks == 0) ? (w0 * b2e0[col] + w1 * b2e1[col]) : 0.f;
#pragma unroll
    for (int mt = 0; mt < 4; ++mt) {
#pragma unroll
      for (int r = 0; r < 4; ++r) {
        const int row = m0 + wm + mt * 16 + kq * 4 + r;
        atomicAdd(&C[(size_t)row * 768 + col], acc[mt][nt][r] + bias);
      }
    }
  }
}

extern "C" void kernel_launch(void* const* d_in, const int* in_sizes, int n_in,
                              void* d_out, int out_size, void* d_ws, size_t ws_size,
                              hipStream_t stream) {
  const float* hidden = (const float*)d_in[0];  // [8,512,768] fp32
  const float* Wg     = (const float*)d_in[1];  // [768,8]
  const float* W1     = (const float*)d_in[2];  // [8,768,3072]
  const float* b1     = (const float*)d_in[3];  // [8,3072]
  const float* W2     = (const float*)d_in[4];  // [8,3072,768]
  const float* b2     = (const float*)d_in[5];  // [8,768]
  float* out = (float*)d_out;                   // [8,512,768] ++ logits [8,8], fp32

  char* ws = (char*)d_ws;
  int*   sel    = (int*)ws;                     // [16]
  float* wsel   = (float*)(ws + 64);            // [16]
  float* pooled = (float*)(ws + 128);           // [8][768] fp32
  u16* hbf  = (u16*)(ws + 32768);               // [8][512][768] bf16
  u16* wT   = hbf + (size_t)8 * 512 * 768;      // [8][3072][768] bf16 (w1t, then w2t)
  u16* hbuf = wT + (size_t)8 * 3072 * 768;      // [16][512][3072] bf16

  float* logits_out = out + (size_t)8 * 512 * 768;

  hipMemsetAsync(ws, 0, 32768, stream);                       // sel/wsel/pooled
  hipMemsetAsync(out, 0, (size_t)out_size * 4, stream);       // atomic accum base
  convert_pool_kernel<<<dim3(64, 8), 192, 0, stream>>>(hidden, hbf, pooled);
  router_final_kernel<<<1, 256, 0, stream>>>(pooled, Wg, logits_out, sel, wsel);
  transpose_kernel<<<dim3(48, 12, 8), 128, 0, stream>>>(W1, wT, 768, 3072);   // [H,F]->[F,H]
  gemm1_kernel<<<dim3(24, 4, 16), 256, 0, stream>>>(hbf, wT, b1, hbuf, sel, wsel);
  transpose_kernel<<<dim3(12, 48, 8), 128, 0, stream>>>(W2, wT, 3072, 768);   // [F,H]->[H,F]
  gemm2_kernel<<<dim3(6, 4, 32), 256, 0, stream>>>(hbuf, wT, b2, out, sel, wsel);
}

// Round 7
// 371.770 us; speedup vs baseline: 1.7247x; 1.7121x over previous
//
#include <hip/hip_runtime.h>

typedef unsigned short u16;
typedef unsigned int u32;
typedef __attribute__((ext_vector_type(8))) short bf16x8;
typedef __attribute__((ext_vector_type(4))) float f32x4;
typedef __attribute__((ext_vector_type(8))) u16 u16x8;
typedef __attribute__((ext_vector_type(4))) u16 u16x4;

#define DEV __device__ __forceinline__

DEV u16 f2bf(float f) {
  u32 x = __float_as_uint(f);
  return (u16)((x + 0x7fffu + ((x >> 16) & 1u)) >> 16);  // RNE
}

// Problem dims: B=8 S=512 H=768 E=8 F=3072 K=2. fp32 I/O; internal bf16 MFMA.
// GEMM staging: global_load_lds (zero VGPR cost — r5/r6 showed VGPR prefetch
// spills to scratch, 600 MB/launch). Bank conflicts fixed by XOR-swizzling the
// 16B chunk slot within each 128B LDS row: slot s of row r holds global chunk
// s^(r&7); b128 fragment reads then hit all 32 banks at the 8-dword/bank floor.

// ---------- convert hidden fp32->bf16 + pooled sums ----------
__global__ void convert_pool_kernel(const float* __restrict__ hidden, u16* __restrict__ hbf,
                                    float* __restrict__ pooled) {
  const int b = blockIdx.y, chunk = blockIdx.x, t = threadIdx.x;  // t in [0,192)
  const size_t base = (size_t)b * 512 * 768 + (size_t)chunk * 8 * 768 + t * 4;
  float ax = 0.f, ay = 0.f, az = 0.f, aw = 0.f;
#pragma unroll
  for (int r = 0; r < 8; ++r) {
    const float4 v = *(const float4*)(hidden + base + r * 768);
    ax += v.x; ay += v.y; az += v.z; aw += v.w;
    u16x4 o; o[0] = f2bf(v.x); o[1] = f2bf(v.y); o[2] = f2bf(v.z); o[3] = f2bf(v.w);
    *(u16x4*)(hbf + base + r * 768) = o;
  }
  float* p = pooled + b * 768 + t * 4;
  atomicAdd(p + 0, ax); atomicAdd(p + 1, ay);
  atomicAdd(p + 2, az); atomicAdd(p + 3, aw);
}

// ---------- router finalize ----------
__global__ void router_final_kernel(const float* __restrict__ pooled, const float* __restrict__ Wg,
                                    float* __restrict__ logits_out, int* __restrict__ sel,
                                    float* __restrict__ wsel) {
  __shared__ float l8[64];
  const int tid = threadIdx.x;
  const int b = tid >> 5, r = tid & 31, e = r >> 2, q = r & 3;
  float p = 0.f;
  for (int h = q * 192; h < q * 192 + 192; ++h) p += pooled[b * 768 + h] * Wg[h * 8 + e];
  p += __shfl_xor(p, 1);
  p += __shfl_xor(p, 2);
  if (q == 0) {
    const float lg = p * (1.f / 512.f);
    l8[b * 8 + e] = lg;
    logits_out[b * 8 + e] = lg;
  }
  __syncthreads();
  if (tid < 8) {
    const int bb = tid;
    float mx = -1e30f;
    for (int i = 0; i < 8; ++i) mx = fmaxf(mx, l8[bb * 8 + i]);
    float w[8], ssum = 0.f;
    for (int i = 0; i < 8; ++i) { w[i] = __expf(l8[bb * 8 + i] - mx); ssum += w[i]; }
    for (int i = 0; i < 8; ++i) w[i] /= ssum;
    int i0 = 0;
    for (int i = 1; i < 8; ++i) if (w[i] > w[i0]) i0 = i;   // first-occurrence ties
    int i1 = (i0 == 0) ? 1 : 0;
    for (int i = 0; i < 8; ++i) if (i != i0 && w[i] > w[i1]) i1 = i;
    sel[bb * 2 + 0] = i0; sel[bb * 2 + 1] = i1;
    wsel[bb * 2 + 0] = w[i0]; wsel[bb * 2 + 1] = w[i1];
  }
}

// ---------- 64x64 tiled transpose, fp32 src -> bf16 dst ----------
__global__ void transpose_kernel(const float* __restrict__ src, u16* __restrict__ dst,
                                 int R, int C) {
  __shared__ u16 tile[64][68];
  const int e = blockIdx.z;
  src += (size_t)e * (size_t)R * C;
  dst += (size_t)e * (size_t)R * C;
  const int r0 = blockIdx.y * 64, c0 = blockIdx.x * 64;
  const int t = threadIdx.x;  // [0,128)
#pragma unroll
  for (int i = 0; i < 8; ++i) {
    const int ch = i * 128 + t;
    const int row = ch >> 4, c4 = (ch & 15) * 4;
    const float4 v = *(const float4*)(src + (size_t)(r0 + row) * C + c0 + c4);
    u16x4 o; o[0] = f2bf(v.x); o[1] = f2bf(v.y); o[2] = f2bf(v.z); o[3] = f2bf(v.w);
    *(u16x4*)(&tile[row][c4]) = o;
  }
  __syncthreads();
  const int cg = t & 15, rg = t >> 4;
  const int c4 = cg * 4, r8 = rg * 8;
  u16x4 rv[8];
#pragma unroll
  for (int j = 0; j < 8; ++j) rv[j] = *(const u16x4*)(&tile[r8 + j][c4]);
#pragma unroll
  for (int i = 0; i < 4; ++i) {
    u16x8 o;
#pragma unroll
    for (int j = 0; j < 8; ++j) o[j] = rv[j][i];
    *(u16x8*)(dst + (size_t)(c0 + c4 + i) * R + r0 + r8) = o;
  }
}

// ---------- GEMM core: global_load_lds staging with XOR-swizzled chunk slots ----------
// LDS tile 128 rows x 64 elems (128 B), unpadded. Chunk slot s (16B) of row r
// holds global k-chunk s^(r&7).
DEV void stage_tile(const u16* __restrict__ gbase, int ld, int row0, int k0,
                    u16* lds, int tid) {
  const int crow = tid >> 3;                       // 0..31 (row within 32-row group)
  const int swz = ((tid & 7) ^ (crow & 7)) * 8;    // swizzled global k-offset (elems)
  const int wbase = tid & ~63;                     // wave-uniform chunk base
#pragma unroll
  for (int i = 0; i < 4; ++i) {
    const u16* g = gbase + (size_t)(row0 + i * 32 + crow) * ld + k0 + swz;
    u16* l = lds + (size_t)(i * 256 + wbase) * 8;  // HW adds lane*16B
    __builtin_amdgcn_global_load_lds((const __attribute__((address_space(1))) void*)g,
                                     (__attribute__((address_space(3))) void*)l, 16, 0, 0);
  }
}

DEV void mfma_step(const u16* As, const u16* Bs, int wm, int wn, int mi, int kq,
                   f32x4 acc[4][4]) {
#pragma unroll
  for (int s2 = 0; s2 < 2; ++s2) {                 // k-chunk base 0 / 4
    bf16x8 af[4], bfr[4];
#pragma unroll
    for (int mt = 0; mt < 4; ++mt) {
      const int row = wm + mt * 16 + mi;
      const int cq = (s2 * 4 + kq) ^ (row & 7);    // swizzled slot
      af[mt] = *(const bf16x8*)(As + row * 64 + cq * 8);
    }
#pragma unroll
    for (int nt = 0; nt < 4; ++nt) {
      const int row = wn + nt * 16 + mi;
      const int cq = (s2 * 4 + kq) ^ (row & 7);
      bfr[nt] = *(const bf16x8*)(Bs + row * 64 + cq * 8);
    }
#pragma unroll
    for (int mt = 0; mt < 4; ++mt)
#pragma unroll
      for (int nt = 0; nt < 4; ++nt)
        acc[mt][nt] = __builtin_amdgcn_mfma_f32_16x16x32_bf16(af[mt], bfr[nt], acc[mt][nt], 0, 0, 0);
  }
}

// ---------- GEMM1: hbuf = wgt * gelu(hbf @ W1[e] + b1[e]), bf16 out ----------
// grid (24 n, 4 m, 16 pairs); K=768 -> 12 steps
__global__ void gemm1_kernel(const u16* __restrict__ hbf, const u16* __restrict__ w1t,
                             const float* __restrict__ b1, u16* __restrict__ hbuf,
                             const int* __restrict__ sel, const float* __restrict__ wsel) {
  __shared__ __align__(16) u16 As[128 * 64];
  __shared__ __align__(16) u16 Bs[128 * 64];
  const int p = blockIdx.z;
  const int b = p >> 1;
  const int e = sel[p];
  const float wgt = wsel[p];
  const u16* A = hbf + (size_t)b * 512 * 768;
  const u16* Bt = w1t + (size_t)e * 3072 * 768;
  const int m0 = blockIdx.y * 128, n0 = blockIdx.x * 128;
  const int tid = threadIdx.x, lane = tid & 63;
  const int wv = tid >> 6;
  const int wm = (wv >> 1) * 64, wn = (wv & 1) * 64;
  const int mi = lane & 15, kq = lane >> 4;

  f32x4 acc[4][4] = {};
  for (int k0 = 0; k0 < 768; k0 += 64) {
    __syncthreads();
    stage_tile(A, 768, m0, k0, As, tid);
    stage_tile(Bt, 768, n0, k0, Bs, tid);
    __syncthreads();
    mfma_step(As, Bs, wm, wn, mi, kq, acc);
  }

  const float* b1e = b1 + e * 3072;
  u16* C = hbuf + (size_t)p * 512 * 3072;
#pragma unroll
  for (int nt = 0; nt < 4; ++nt) {
    const int col = n0 + wn + nt * 16 + mi;
    const float bias = b1e[col];
#pragma unroll
    for (int mt = 0; mt < 4; ++mt) {
#pragma unroll
      for (int r = 0; r < 4; ++r) {
        const int row = m0 + wm + mt * 16 + kq * 4 + r;  // C/D: col=lane&15, row=quad*4+reg
        const float x = acc[mt][nt][r] + bias;
        const float g = 0.5f * x * (1.f + erff(x * 0.70710678118654752f));  // exact GELU
        C[(size_t)row * 3072 + col] = f2bf(wgt * g);
      }
    }
  }
}

// ---------- GEMM2 split-K x4: out[b] += hbuf_k @ W2[e_k] (fp32 atomics) ----------
// grid (6 n, 4 m, 32 = 8 b x 4 ks); each split = 24 steps; ks==0 adds weighted bias
// (out memset to 0 before launch).
__global__ void gemm2_kernel(const u16* __restrict__ hbuf, const u16* __restrict__ w2t,
                             const float* __restrict__ b2, float* __restrict__ out,
                             const int* __restrict__ sel, const float* __restrict__ wsel) {
  __shared__ __align__(16) u16 As[128 * 64];
  __shared__ __align__(16) u16 Bs[128 * 64];
  const int z = blockIdx.z;
  const int b = z >> 2, ks = z & 3;
  const int kslot = ks >> 1;
  const int e = sel[b * 2 + kslot];
  const u16* A = hbuf + (size_t)(b * 2 + kslot) * 512 * 3072;
  const u16* Bt = w2t + (size_t)e * 768 * 3072;
  const int kbase = (ks & 1) * 1536;
  const int m0 = blockIdx.y * 128, n0 = blockIdx.x * 128;
  const int tid = threadIdx.x, lane = tid & 63;
  const int wv = tid >> 6;
  const int wm = (wv >> 1) * 64, wn = (wv & 1) * 64;
  const int mi = lane & 15, kq = lane >> 4;

  f32x4 acc[4][4] = {};
  for (int t = 0; t < 24; ++t) {
    const int k0 = kbase + t * 64;
    __syncthreads();
    stage_tile(A, 3072, m0, k0, As, tid);
    stage_tile(Bt, 3072, n0, k0, Bs, tid);
    __syncthreads();
    mfma_step(As, Bs, wm, wn, mi, kq, acc);
  }

  float* C = out + (size_t)b * 512 * 768;
  const float w0 = wsel[b * 2 + 0], w1 = wsel[b * 2 + 1];
  const float* b2e0 = b2 + sel[b * 2 + 0] * 768;
  const float* b2e1 = b2 + sel[b * 2 + 1] * 768;
#pragma unroll
  for (int nt = 0; nt < 4; ++nt) {
    const int col = n0 + wn + nt * 16 + mi;
    const float bias = (ks == 0) ? (w0 * b2e0[col] + w1 * b2e1[col]) : 0.f;
#pragma unroll
    for (int mt = 0; mt < 4; ++mt) {
#pragma unroll
      for (int r = 0; r < 4; ++r) {
        const int row = m0 + wm + mt * 16 + kq * 4 + r;
        atomicAdd(&C[(size_t)row * 768 + col], acc[mt][nt][r] + bias);
      }
    }
  }
}

extern "C" void kernel_launch(void* const* d_in, const int* in_sizes, int n_in,
                              void* d_out, int out_size, void* d_ws, size_t ws_size,
                              hipStream_t stream) {
  const float* hidden = (const float*)d_in[0];  // [8,512,768] fp32
  const float* Wg     = (const float*)d_in[1];  // [768,8]
  const float* W1     = (const float*)d_in[2];  // [8,768,3072]
  const float* b1     = (const float*)d_in[3];  // [8,3072]
  const float* W2     = (const float*)d_in[4];  // [8,3072,768]
  const float* b2     = (const float*)d_in[5];  // [8,768]
  float* out = (float*)d_out;                   // [8,512,768] ++ logits [8,8], fp32

  char* ws = (char*)d_ws;
  int*   sel    = (int*)ws;                     // [16]
  float* wsel   = (float*)(ws + 64);            // [16]
  float* pooled = (float*)(ws + 128);           // [8][768] fp32
  u16* hbf  = (u16*)(ws + 32768);               // [8][512][768] bf16
  u16* wT   = hbf + (size_t)8 * 512 * 768;      // [8][3072][768] bf16 (w1t, then w2t)
  u16* hbuf = wT + (size_t)8 * 3072 * 768;      // [16][512][3072] bf16

  float* logits_out = out + (size_t)8 * 512 * 768;

  hipMemsetAsync(ws, 0, 32768, stream);                       // sel/wsel/pooled
  hipMemsetAsync(out, 0, (size_t)out_size * 4, stream);       // atomic accum base
  convert_pool_kernel<<<dim3(64, 8), 192, 0, stream>>>(hidden, hbf, pooled);
  router_final_kernel<<<1, 256, 0, stream>>>(pooled, Wg, logits_out, sel, wsel);
  transpose_kernel<<<dim3(48, 12, 8), 128, 0, stream>>>(W1, wT, 768, 3072);   // [H,F]->[F,H]
  gemm1_kernel<<<dim3(24, 4, 16), 256, 0, stream>>>(hbf, wT, b1, hbuf, sel, wsel);
  transpose_kernel<<<dim3(12, 48, 8), 128, 0, stream>>>(W2, wT, 3072, 768);   // [F,H]->[H,F]
  gemm2_kernel<<<dim3(6, 4, 32), 256, 0, stream>>>(hbuf, wT, b2, out, sel, wsel);
}

// Round 8
// 348.457 us; speedup vs baseline: 1.8401x; 1.0669x over previous
//
#include <hip/hip_runtime.h>

typedef unsigned short u16;
typedef unsigned int u32;
typedef __attribute__((ext_vector_type(8))) short bf16x8;
typedef __attribute__((ext_vector_type(4))) float f32x4;
typedef __attribute__((ext_vector_type(8))) u16 u16x8;
typedef __attribute__((ext_vector_type(4))) u16 u16x4;

#define DEV __device__ __forceinline__

DEV u16 f2bf(float f) {
  u32 x = __float_as_uint(f);
  return (u16)((x + 0x7fffu + ((x >> 16) & 1u)) >> 16);  // RNE
}

// B=8 S=512 H=768 E=8 F=3072 K=2. fp32 I/O; bf16 MFMA internals.
// r7 learnings kept: global_load_lds staging (no VGPR prefetch — spills),
// XOR-swizzled LDS chunk slots (bank conflicts = 0).
// New: XCD-aware 1D block remap (bid&7 = XCD, each XCD owns one batch's
// sub-problem => per-XCD L2 reuse); transposes fused into other grids for
// overlap (single stream => separate kernels never overlap).

// ---------- 128x64 tile transpose: fp32 src -> bf16 dst (256 thr) ----------
DEV void transpose_tile(const float* __restrict__ src, u16* __restrict__ dst,
                        int R, int C, int r0, int c0, int t, u16* tile /*128*68*/) {
#pragma unroll
  for (int i = 0; i < 8; ++i) {
    const int idx = i * 256 + t;
    const int row = idx >> 4, c4 = (idx & 15) * 4;
    const float4 v = *(const float4*)(src + (size_t)(r0 + row) * C + c0 + c4);
    u16x4 o; o[0] = f2bf(v.x); o[1] = f2bf(v.y); o[2] = f2bf(v.z); o[3] = f2bf(v.w);
    *(u16x4*)(tile + row * 68 + c4) = o;
  }
  __syncthreads();
#pragma unroll
  for (int i = 0; i < 4; ++i) {
    const int widx = i * 256 + t;
    const int c = widx >> 4, r8 = (widx & 15) * 8;
    u16x8 o;
#pragma unroll
    for (int j = 0; j < 8; ++j) o[j] = tile[(r8 + j) * 68 + c];
    *(u16x8*)(dst + (size_t)(c0 + c) * R + r0 + r8) = o;
  }
}

// ---------- prep: [0,2304) transpose W1 tiles; [2304,2816) convert+pool ----------
__global__ void prep_kernel(const float* __restrict__ W1, u16* __restrict__ w1t,
                            const float* __restrict__ hidden, u16* __restrict__ hbf,
                            float* __restrict__ pooled) {
  __shared__ __align__(16) u16 smem[128 * 68];
  const int bid = blockIdx.x, t = threadIdx.x;
  if (bid < 2304) {  // W1 [768,3072] -> [3072,768], 288 tiles/expert
    const int e = bid / 288, rem = bid % 288;
    const int r0 = (rem / 48) * 128, c0 = (rem % 48) * 64;
    transpose_tile(W1 + (size_t)e * 768 * 3072, w1t + (size_t)e * 768 * 3072,
                   768, 3072, r0, c0, t, smem);
    return;
  }
  if (t >= 192) return;  // convert role uses 192 lanes
  const int u = bid - 2304;                 // 512 units: 8 rows each
  const int b = u >> 6, chunk = u & 63;
  const size_t base = (size_t)b * 512 * 768 + (size_t)chunk * 8 * 768 + t * 4;
  float ax = 0.f, ay = 0.f, az = 0.f, aw = 0.f;
#pragma unroll
  for (int r = 0; r < 8; ++r) {
    const float4 v = *(const float4*)(hidden + base + r * 768);
    ax += v.x; ay += v.y; az += v.z; aw += v.w;
    u16x4 o; o[0] = f2bf(v.x); o[1] = f2bf(v.y); o[2] = f2bf(v.z); o[3] = f2bf(v.w);
    *(u16x4*)(hbf + base + r * 768) = o;
  }
  float* p = pooled + b * 768 + t * 4;
  atomicAdd(p + 0, ax); atomicAdd(p + 1, ay);
  atomicAdd(p + 2, az); atomicAdd(p + 3, aw);
}

// ---------- standalone transpose W2 (small-ws fallback path) ----------
__global__ void transpose_w2_kernel(const float* __restrict__ W2, u16* __restrict__ w2t) {
  __shared__ __align__(16) u16 smem[128 * 68];
  const int bid = blockIdx.x, t = threadIdx.x;
  const int e = bid / 288, rem = bid % 288;
  const int r0 = (rem / 12) * 128, c0 = (rem % 12) * 64;
  transpose_tile(W2 + (size_t)e * 3072 * 768, w2t + (size_t)e * 3072 * 768,
                 3072, 768, r0, c0, t, smem);
}

// ---------- router finalize ----------
__global__ void router_final_kernel(const float* __restrict__ pooled, const float* __restrict__ Wg,
                                    float* __restrict__ logits_out, int* __restrict__ sel,
                                    float* __restrict__ wsel) {
  __shared__ float l8[64];
  const int tid = threadIdx.x;
  const int b = tid >> 5, r = tid & 31, e = r >> 2, q = r & 3;
  float p = 0.f;
  for (int h = q * 192; h < q * 192 + 192; ++h) p += pooled[b * 768 + h] * Wg[h * 8 + e];
  p += __shfl_xor(p, 1);
  p += __shfl_xor(p, 2);
  if (q == 0) {
    const float lg = p * (1.f / 512.f);
    l8[b * 8 + e] = lg;
    logits_out[b * 8 + e] = lg;
  }
  __syncthreads();
  if (tid < 8) {
    const int bb = tid;
    float mx = -1e30f;
    for (int i = 0; i < 8; ++i) mx = fmaxf(mx, l8[bb * 8 + i]);
    float w[8], ssum = 0.f;
    for (int i = 0; i < 8; ++i) { w[i] = __expf(l8[bb * 8 + i] - mx); ssum += w[i]; }
    for (int i = 0; i < 8; ++i) w[i] /= ssum;
    int i0 = 0;
    for (int i = 1; i < 8; ++i) if (w[i] > w[i0]) i0 = i;   // first-occurrence ties
    int i1 = (i0 == 0) ? 1 : 0;
    for (int i = 0; i < 8; ++i) if (i != i0 && w[i] > w[i1]) i1 = i;
    sel[bb * 2 + 0] = i0; sel[bb * 2 + 1] = i1;
    wsel[bb * 2 + 0] = w[i0]; wsel[bb * 2 + 1] = w[i1];
  }
}

// ---------- GEMM core: global_load_lds staging, XOR-swizzled slots ----------
DEV void stage_tile(const u16* __restrict__ gbase, int ld, int row0, int k0,
                    u16* lds, int tid) {
  const int crow = tid >> 3;
  const int swz = ((tid & 7) ^ (crow & 7)) * 8;
  const int wbase = tid & ~63;
#pragma unroll
  for (int i = 0; i < 4; ++i) {
    const u16* g = gbase + (size_t)(row0 + i * 32 + crow) * ld + k0 + swz;
    u16* l = lds + (size_t)(i * 256 + wbase) * 8;
    __builtin_amdgcn_global_load_lds((const __attribute__((address_space(1))) void*)g,
                                     (__attribute__((address_space(3))) void*)l, 16, 0, 0);
  }
}

DEV void mfma_step(const u16* As, const u16* Bs, int wm, int wn, int mi, int kq,
                   f32x4 acc[4][4]) {
#pragma unroll
  for (int s2 = 0; s2 < 2; ++s2) {
    bf16x8 af[4], bfr[4];
#pragma unroll
    for (int mt = 0; mt < 4; ++mt) {
      const int row = wm + mt * 16 + mi;
      const int cq = (s2 * 4 + kq) ^ (row & 7);
      af[mt] = *(const bf16x8*)(As + row * 64 + cq * 8);
    }
#pragma unroll
    for (int nt = 0; nt < 4; ++nt) {
      const int row = wn + nt * 16 + mi;
      const int cq = (s2 * 4 + kq) ^ (row & 7);
      bfr[nt] = *(const bf16x8*)(Bs + row * 64 + cq * 8);
    }
#pragma unroll
    for (int mt = 0; mt < 4; ++mt)
#pragma unroll
      for (int nt = 0; nt < 4; ++nt)
        acc[mt][nt] = __builtin_amdgcn_mfma_f32_16x16x32_bf16(af[mt], bfr[nt], acc[mt][nt], 0, 0, 0);
  }
}

// ---------- GEMM1 (+fused W2 transpose when nT>0) ----------
// bid<nT: transpose W2 tile. bid>=nT: gemm, XCD-remapped:
// xcd=bid'&7, slot=bid'>>3 (0..191), z = xcd*2 + slot/96, t=slot%96, m=t/24, n=t%24.
__global__ void gemm1_kernel(const u16* __restrict__ hbf, const u16* __restrict__ w1t,
                             const float* __restrict__ b1, u16* __restrict__ hbuf,
                             const int* __restrict__ sel, const float* __restrict__ wsel,
                             const float* __restrict__ W2, u16* __restrict__ w2t, int nT) {
  __shared__ __align__(16) u16 smem[2 * 128 * 64];
  const int tid = threadIdx.x;
  int bid = blockIdx.x;
  if (bid < nT) {  // W2 [3072,768] -> [768,3072]
    const int e = bid / 288, rem = bid % 288;
    const int r0 = (rem / 12) * 128, c0 = (rem % 12) * 64;
    transpose_tile(W2 + (size_t)e * 3072 * 768, w2t + (size_t)e * 3072 * 768,
                   3072, 768, r0, c0, tid, smem);
    return;
  }
  bid -= nT;
  u16* As = smem; u16* Bs = smem + 128 * 64;
  const int xcd = bid & 7, slot = bid >> 3;
  const int p = xcd * 2 + slot / 96;        // pair index: XCD x owns batch x's 2 pairs
  const int tt = slot % 96;
  const int m0 = (tt / 24) * 128, n0 = (tt % 24) * 128;
  const int b = p >> 1;
  const int e = sel[p];
  const float wgt = wsel[p];
  const u16* A = hbf + (size_t)b * 512 * 768;
  const u16* Bt = w1t + (size_t)e * 3072 * 768;
  const int lane = tid & 63, wv = tid >> 6;
  const int wm = (wv >> 1) * 64, wn = (wv & 1) * 64;
  const int mi = lane & 15, kq = lane >> 4;

  f32x4 acc[4][4] = {};
  for (int k0 = 0; k0 < 768; k0 += 64) {
    __syncthreads();
    stage_tile(A, 768, m0, k0, As, tid);
    stage_tile(Bt, 768, n0, k0, Bs, tid);
    __syncthreads();
    mfma_step(As, Bs, wm, wn, mi, kq, acc);
  }

  const float* b1e = b1 + e * 3072;
  u16* C = hbuf + (size_t)p * 512 * 3072;
#pragma unroll
  for (int nt = 0; nt < 4; ++nt) {
    const int col = n0 + wn + nt * 16 + mi;
    const float bias = b1e[col];
#pragma unroll
    for (int mt = 0; mt < 4; ++mt) {
#pragma unroll
      for (int r = 0; r < 4; ++r) {
        const int row = m0 + wm + mt * 16 + kq * 4 + r;  // C/D: col=lane&15, row=quad*4+reg
        const float x = acc[mt][nt][r] + bias;
        const float g = 0.5f * x * (1.f + erff(x * 0.70710678118654752f));  // exact GELU
        C[(size_t)row * 3072 + col] = f2bf(wgt * g);
      }
    }
  }
}

// ---------- GEMM2 split-K x4, XCD-remapped, fp32 atomics ----------
// grid 768: xcd=bid&7 (= batch), slot=bid>>3 (0..95), ks=slot/24, t=slot%24,
// m=t/6, n=t%6. ks==0 adds weighted bias (out pre-zeroed).
__global__ void gemm2_kernel(const u16* __restrict__ hbuf, const u16* __restrict__ w2t,
                             const float* __restrict__ b2, float* __restrict__ out,
                             const int* __restrict__ sel, const float* __restrict__ wsel) {
  __shared__ __align__(16) u16 As[128 * 64];
  __shared__ __align__(16) u16 Bs[128 * 64];
  const int bid = blockIdx.x, tid = threadIdx.x;
  const int b = bid & 7, slot = bid >> 3;
  const int ks = slot / 24, tt = slot % 24;
  const int m0 = (tt / 6) * 128, n0 = (tt % 6) * 128;
  const int kslot = ks >> 1;
  const int e = sel[b * 2 + kslot];
  const u16* A = hbuf + (size_t)(b * 2 + kslot) * 512 * 3072;
  const u16* Bt = w2t + (size_t)e * 768 * 3072;
  const int kbase = (ks & 1) * 1536;
  const int lane = tid & 63, wv = tid >> 6;
  const int wm = (wv >> 1) * 64, wn = (wv & 1) * 64;
  const int mi = lane & 15, kq = lane >> 4;

  f32x4 acc[4][4] = {};
  for (int t = 0; t < 24; ++t) {
    const int k0 = kbase + t * 64;
    __syncthreads();
    stage_tile(A, 3072, m0, k0, As, tid);
    stage_tile(Bt, 3072, n0, k0, Bs, tid);
    __syncthreads();
    mfma_step(As, Bs, wm, wn, mi, kq, acc);
  }

  float* C = out + (size_t)b * 512 * 768;
  const float w0 = wsel[b * 2 + 0], w1 = wsel[b * 2 + 1];
  const float* b2e0 = b2 + sel[b * 2 + 0] * 768;
  const float* b2e1 = b2 + sel[b * 2 + 1] * 768;
#pragma unroll
  for (int nt = 0; nt < 4; ++nt) {
    const int col = n0 + wn + nt * 16 + mi;
    const float bias = (ks == 0) ? (w0 * b2e0[col] + w1 * b2e1[col]) : 0.f;
#pragma unroll
    for (int mt = 0; mt < 4; ++mt) {
#pragma unroll
      for (int r = 0; r < 4; ++r) {
        const int row = m0 + wm + mt * 16 + kq * 4 + r;
        atomicAdd(&C[(size_t)row * 768 + col], acc[mt][nt][r] + bias);
      }
    }
  }
}

extern "C" void kernel_launch(void* const* d_in, const int* in_sizes, int n_in,
                              void* d_out, int out_size, void* d_ws, size_t ws_size,
                              hipStream_t stream) {
  const float* hidden = (const float*)d_in[0];  // [8,512,768] fp32
  const float* Wg     = (const float*)d_in[1];  // [768,8]
  const float* W1     = (const float*)d_in[2];  // [8,768,3072]
  const float* b1     = (const float*)d_in[3];  // [8,3072]
  const float* W2     = (const float*)d_in[4];  // [8,3072,768]
  const float* b2     = (const float*)d_in[5];  // [8,768]
  float* out = (float*)d_out;                   // [8,512,768] ++ logits [8,8]

  char* ws = (char*)d_ws;
  int*   sel    = (int*)ws;
  float* wsel   = (float*)(ws + 64);
  float* pooled = (float*)(ws + 128);
  u16* hbf = (u16*)(ws + 32768);                         // 6.29 MB
  u16* w1t = hbf + (size_t)8 * 512 * 768;                // 37.75 MB
  const size_t WSZ = (size_t)8 * 3072 * 768;
  // big-ws layout: separate w2t (transposeW2 overlaps gemm1); else overlay w1t slot
  const size_t need_big = 32768 + 6291456 + 2 * 75497472 / 2 + 2 * WSZ * 2;  // see below
  const bool big = ws_size >= (size_t)(32768 + 6291456 + 37748736 + 37748736 + 50331648);
  u16* w2t  = big ? (w1t + WSZ) : w1t;
  u16* hbuf = big ? (w2t + WSZ) : (w1t + WSZ);
  (void)need_big;

  float* logits_out = out + (size_t)8 * 512 * 768;

  hipMemsetAsync(ws, 0, 32768, stream);                  // sel/wsel/pooled
  hipMemsetAsync(out, 0, (size_t)out_size * 4, stream);  // atomic accum base
  prep_kernel<<<2816, 256, 0, stream>>>(W1, w1t, hidden, hbf, pooled);
  router_final_kernel<<<1, 256, 0, stream>>>(pooled, Wg, logits_out, sel, wsel);
  if (big) {
    gemm1_kernel<<<2304 + 1536, 256, 0, stream>>>(hbf, w1t, b1, hbuf, sel, wsel, W2, w2t, 2304);
  } else {
    gemm1_kernel<<<1536, 256, 0, stream>>>(hbf, w1t, b1, hbuf, sel, wsel, W2, w2t, 0);
    transpose_w2_kernel<<<2304, 256, 0, stream>>>(W2, w2t);
  }
  gemm2_kernel<<<768, 256, 0, stream>>>(hbuf, w2t, b2, out, sel, wsel);
}